// Round 2
// baseline (682.786 us; speedup 1.0000x reference)
//
#include <hip/hip_runtime.h>

// B=32, S=577, D=768, H=12, Dh=64. fp32 in/out, bf16 MFMA compute.
#define NB 32
#define SEQ 577
#define SP 640      // padded seq (5*128, 10*64)
#define DM 768
#define NH 12
#define DH 64

typedef __attribute__((ext_vector_type(8))) short bf16x8;   // K=32 MFMA A/B frag
typedef __attribute__((ext_vector_type(4))) short bf16x4;   // K=16 MFMA A/B frag
typedef __attribute__((ext_vector_type(4))) float f32x4;
typedef __attribute__((ext_vector_type(2))) unsigned int u32x2;
typedef unsigned short u16;

__device__ __forceinline__ u16 f2bf(float f) {  // RNE float->bf16
  unsigned int u = __builtin_bit_cast(unsigned int, f);
  u += 0x7fffu + ((u >> 16) & 1u);
  return (u16)(u >> 16);
}

// pack two fp32 -> bf16 pair (round-half-up) in one v_perm
__device__ __forceinline__ unsigned int pack_bf2(float a, float b) {
  unsigned int ua = __builtin_bit_cast(unsigned int, a) + 0x8000u;
  unsigned int ub = __builtin_bit_cast(unsigned int, b) + 0x8000u;
  return __builtin_amdgcn_perm(ub, ua, 0x07060302u);  // lo16=bf(a), hi16=bf(b)
}

__device__ __forceinline__ void g2l16(const void* g, void* lds) {
  __builtin_amdgcn_global_load_lds(
      (const __attribute__((address_space(1))) void*)g,
      (__attribute__((address_space(3))) void*)lds, 16, 0, 0);
}

// ---- kernel 1: fp32 -> bf16 cast of hidden_states -------------------------
__global__ void cvt_x_kernel(const float* __restrict__ X, u16* __restrict__ Xb, int n4) {
  int i = blockIdx.x * 256 + threadIdx.x;
  if (i >= n4) return;
  f32x4 v = *reinterpret_cast<const f32x4*>(X + (size_t)i * 4);
  u32x2 p;
  p[0] = (unsigned)f2bf(v[0]) | ((unsigned)f2bf(v[1]) << 16);
  p[1] = (unsigned)f2bf(v[2]) | ((unsigned)f2bf(v[3]) << 16);
  *reinterpret_cast<u32x2*>(Xb + (size_t)i * 4) = p;
}

// ---- kernel 2: cast + transpose weights: Wt[qkv][n][k] --------------------
__global__ void cvt_w_kernel(const float* __restrict__ Wq, const float* __restrict__ Wk,
                             const float* __restrict__ Wv, u16* __restrict__ Wt) {
  int idx = blockIdx.x * 256 + threadIdx.x;
  int m = blockIdx.y;
  const float* W = (m == 0) ? Wq : (m == 1) ? Wk : Wv;
  int k = idx / DM, n = idx - k * DM;
  Wt[(size_t)m * DM * DM + (size_t)n * DM + k] = f2bf(W[idx]);
}

// ---- kernel 3: fused QKV GEMM (bf16 MFMA, 128x128 tile, BK=32) ------------
__global__ __launch_bounds__(256)
void qkv_gemm_kernel(const u16* __restrict__ Xb, const u16* __restrict__ Wt,
                     const float* __restrict__ bq, const float* __restrict__ bk,
                     const float* __restrict__ bv,
                     u16* __restrict__ Qw, u16* __restrict__ Kw, u16* __restrict__ Vw) {
  __shared__ alignas(16) u16 As[128 * 32];
  __shared__ alignas(16) u16 Bs[128 * 32];

  const int tid = threadIdx.x;
  const int lane = tid & 63;
  const int wid = tid >> 6;
  const int wr = wid >> 1, wc = wid & 1;
  const int l15 = lane & 15, lq = lane >> 4;

  const int mt = blockIdx.x;
  const int nt = blockIdx.y;
  const int qkv = blockIdx.z;

  const int b = mt / 5;
  const int t0 = (mt - b * 5) * 128;
  const int n0 = nt * 128;

  const u16* Wm = Wt + (size_t)qkv * DM * DM;
  const float* bias = (qkv == 0) ? bq : (qkv == 1) ? bk : bv;

  int tA0 = t0 + wid * 16 + l15;
  int tA1 = t0 + (wid + 4) * 16 + l15;
  int xr0 = b * SEQ + (tA0 < SEQ ? tA0 : SEQ - 1);
  int xr1 = b * SEQ + (tA1 < SEQ ? tA1 : SEQ - 1);
  const u16* gA0 = Xb + (size_t)xr0 * DM + lq * 8;
  const u16* gA1 = Xb + (size_t)xr1 * DM + lq * 8;
  const u16* gB0 = Wm + (size_t)(n0 + wid * 16 + l15) * DM + lq * 8;
  const u16* gB1 = Wm + (size_t)(n0 + (wid + 4) * 16 + l15) * DM + lq * 8;
  u16* lA0 = &As[wid * 512];
  u16* lA1 = &As[(wid + 4) * 512];
  u16* lB0 = &Bs[wid * 512];
  u16* lB1 = &Bs[(wid + 4) * 512];

  f32x4 acc[4][4];
#pragma unroll
  for (int i = 0; i < 4; ++i)
#pragma unroll
    for (int j = 0; j < 4; ++j)
#pragma unroll
      for (int r = 0; r < 4; ++r) acc[i][j][r] = 0.0f;

  for (int k0 = 0; k0 < DM; k0 += 32) {
    g2l16(gA0 + k0, lA0);
    g2l16(gA1 + k0, lA1);
    g2l16(gB0 + k0, lB0);
    g2l16(gB1 + k0, lB1);
    __syncthreads();
    bf16x8 af[4], bfq[4];
#pragma unroll
    for (int i = 0; i < 4; ++i)
      af[i] = *reinterpret_cast<const bf16x8*>(&As[((wr * 4 + i) * 64 + lane) * 8]);
#pragma unroll
    for (int j = 0; j < 4; ++j)
      bfq[j] = *reinterpret_cast<const bf16x8*>(&Bs[((wc * 4 + j) * 64 + lane) * 8]);
#pragma unroll
    for (int i = 0; i < 4; ++i)
#pragma unroll
      for (int j = 0; j < 4; ++j)
        acc[i][j] = __builtin_amdgcn_mfma_f32_16x16x32_bf16(af[i], bfq[j], acc[i][j], 0, 0, 0);
    __syncthreads();
  }

  const float sfold = 0.18033688011112042f;  // (1/sqrt(64)) * log2(e)
#pragma unroll
  for (int j = 0; j < 4; ++j) {
    int col = n0 + wc * 64 + j * 16 + l15;
    int h = col >> 6;
    int d = col & 63;
    float bb = bias[col];
#pragma unroll
    for (int i = 0; i < 4; ++i) {
      int trow = t0 + wr * 64 + i * 16 + lq * 4;
      if (qkv == 2) {
        float v0 = acc[i][j][0] + bb, v1 = acc[i][j][1] + bb;
        float v2 = acc[i][j][2] + bb, v3 = acc[i][j][3] + bb;
        u32x2 p;
        p[0] = (unsigned)f2bf(v0) | ((unsigned)f2bf(v1) << 16);
        p[1] = (unsigned)f2bf(v2) | ((unsigned)f2bf(v3) << 16);
        size_t o = ((size_t)(b * NH + h) * DH + d) * SP + trow;
        *reinterpret_cast<u32x2*>(Vw + o) = p;
      } else {
        u16* dst = ((qkv == 0) ? Qw : Kw) + ((size_t)(b * NH + h) * SP + trow) * DH + d;
#pragma unroll
        for (int r = 0; r < 4; ++r) {
          float v = acc[i][j][r] + bb;
          if (qkv == 0) v *= sfold;
          dst[r * DH] = f2bf(v);
        }
      }
    }
  }
}

// ---- kernel 4: flash attention v2 (S^T formulation, zero barriers) --------
// Per wave: 16 queries (q = l15 column of S^T), 64-key chunks.
// S^T = K·Q^T  (A=K-frag, B=Q-frag) -> lane holds keys 16t+4lq+r of query l15.
// Softmax: in-register over 16 vals + shfl_xor(16,32). P stays in-lane:
// it IS the B-frag of the K=16 PV MFMA (O^T = Vt·P^T). No LDS in the loop.
#if __has_builtin(__builtin_amdgcn_mfma_f32_16x16x16bf16_1k)
#define MFMA16(a, b, c) __builtin_amdgcn_mfma_f32_16x16x16bf16_1k(a, b, c, 0, 0, 0)
#define HAVE_MFMA16 1
#elif __has_builtin(__builtin_amdgcn_mfma_f32_16x16x16_bf16)
#define MFMA16(a, b, c) __builtin_amdgcn_mfma_f32_16x16x16_bf16(a, b, c, 0, 0, 0)
#define HAVE_MFMA16 1
#else
#define HAVE_MFMA16 0
#endif

__global__ __launch_bounds__(256, 3)
void attn_kernel(const u16* __restrict__ Qw, const u16* __restrict__ Kw,
                 const u16* __restrict__ Vw, float* __restrict__ out) {
  __shared__ alignas(16) float Ol[4][16 * 68];  // epilogue transpose, per-wave region

  const int tid = threadIdx.x;
  const int lane = tid & 63;
  const int wid = tid >> 6;
  const int l15 = lane & 15, lq = lane >> 4;
  const int bh = blockIdx.y;
  const int b = bh / NH;
  const int h = bh - b * NH;
  const int q0 = blockIdx.x * 64 + wid * 16;

  const u16* Qb = Qw + (size_t)bh * SP * DH;
  const u16* Kb = Kw + (size_t)bh * SP * DH;
  const u16* Vb = Vw + (size_t)bh * DH * SP;

  // Q as B-operand frag: B[n=q=l15][k=8*lq+j]
  bf16x8 qf0 = *reinterpret_cast<const bf16x8*>(&Qb[(q0 + l15) * DH + lq * 8]);
  bf16x8 qf1 = *reinterpret_cast<const bf16x8*>(&Qb[(q0 + l15) * DH + 32 + lq * 8]);

  float mrow = -__builtin_inff();
  float lrow = 0.0f;
  f32x4 acc[4];  // O^T tiles: d = 16*dt + 4*lq + r, q = l15
#pragma unroll
  for (int dt = 0; dt < 4; ++dt)
#pragma unroll
    for (int r = 0; r < 4; ++r) acc[dt][r] = 0.0f;

  for (int c0 = 0; c0 < SP; c0 += 64) {
    // --- S^T: 4 key-tiles of 16 ---
    f32x4 s[4];
#pragma unroll
    for (int t = 0; t < 4; ++t) {
      bf16x8 kf0 = *reinterpret_cast<const bf16x8*>(&Kb[(c0 + t * 16 + l15) * DH + lq * 8]);
      bf16x8 kf1 = *reinterpret_cast<const bf16x8*>(&Kb[(c0 + t * 16 + l15) * DH + 32 + lq * 8]);
      f32x4 z;
#pragma unroll
      for (int r = 0; r < 4; ++r) z[r] = 0.0f;
      z = __builtin_amdgcn_mfma_f32_16x16x32_bf16(kf0, qf0, z, 0, 0, 0);
      z = __builtin_amdgcn_mfma_f32_16x16x32_bf16(kf1, qf1, z, 0, 0, 0);
      s[t] = z;
    }
    // --- mask padded keys (only last chunk; uniform branch) ---
    if (c0 + 64 > SEQ) {
#pragma unroll
      for (int t = 0; t < 4; ++t)
#pragma unroll
        for (int r = 0; r < 4; ++r) {
          int key = c0 + t * 16 + lq * 4 + r;
          s[t][r] = (key < SEQ) ? s[t][r] : -__builtin_inff();
        }
    }
    // --- online softmax (per-query = per l15 column; reduce regs then lq lanes)
    float mx = s[0][0];
#pragma unroll
    for (int t = 0; t < 4; ++t)
#pragma unroll
      for (int r = 0; r < 4; ++r) mx = fmaxf(mx, s[t][r]);
    mx = fmaxf(mx, __shfl_xor(mx, 16));
    mx = fmaxf(mx, __shfl_xor(mx, 32));
    float mn = fmaxf(mrow, mx);
    float alpha = __builtin_amdgcn_exp2f(mrow - mn);  // first chunk: exp2(-inf)=0
    mrow = mn;

    float p[4][4];
    float sm = 0.0f;
#pragma unroll
    for (int t = 0; t < 4; ++t)
#pragma unroll
      for (int r = 0; r < 4; ++r) {
        p[t][r] = __builtin_amdgcn_exp2f(s[t][r] - mn);
        sm += p[t][r];
      }
    sm += __shfl_xor(sm, 16);
    sm += __shfl_xor(sm, 32);
    lrow = lrow * alpha + sm;

    // pack P -> bf16 pairs (in-lane; this is already the K=16 B-frag layout)
    unsigned int pku[4][2];
#pragma unroll
    for (int t = 0; t < 4; ++t) {
      pku[t][0] = pack_bf2(p[t][0], p[t][1]);
      pku[t][1] = pack_bf2(p[t][2], p[t][3]);
    }

#if HAVE_MFMA16
    // --- PV: O^T = Vt · P^T, K=16 MFMA, zero cross-lane movement ---
#pragma unroll
    for (int dt = 0; dt < 4; ++dt) {
      f32x4 a = acc[dt];
#pragma unroll
      for (int r = 0; r < 4; ++r) a[r] *= alpha;
#pragma unroll
      for (int t = 0; t < 4; ++t) {
        bf16x4 vf = *reinterpret_cast<const bf16x4*>(
            &Vb[(dt * 16 + l15) * SP + c0 + t * 16 + lq * 4]);
        bf16x4 pf = __builtin_bit_cast(bf16x4, u32x2{pku[t][0], pku[t][1]});
        a = MFMA16(vf, pf, a);
      }
      acc[dt] = a;
    }
#else
    // --- fallback: K=32 MFMA, B-frag built with 16 bpermutes ---
    unsigned int bfrag[2][4];
#pragma unroll
    for (int hh = 0; hh < 2; ++hh)
#pragma unroll
      for (int w = 0; w < 4; ++w) {
        int srcl = l15 + 16 * (2 * (lq & 1) + (w >> 1));
        unsigned int lo = (unsigned int)__shfl((int)pku[2 * hh][w & 1], srcl);
        unsigned int hi = (unsigned int)__shfl((int)pku[2 * hh + 1][w & 1], srcl);
        bfrag[hh][w] = (lq < 2) ? lo : hi;
      }
#pragma unroll
    for (int dt = 0; dt < 4; ++dt) {
      f32x4 a = acc[dt];
#pragma unroll
      for (int r = 0; r < 4; ++r) a[r] *= alpha;
#pragma unroll
      for (int hh = 0; hh < 2; ++hh) {
        bf16x8 vf = *reinterpret_cast<const bf16x8*>(
            &Vb[(dt * 16 + l15) * SP + c0 + hh * 32 + lq * 8]);
        typedef __attribute__((ext_vector_type(4))) unsigned int u32x4;
        u32x4 pw = {bfrag[hh][0], bfrag[hh][1], bfrag[hh][2], bfrag[hh][3]};
        a = __builtin_amdgcn_mfma_f32_16x16x32_bf16(vf, __builtin_bit_cast(bf16x8, pw), a, 0, 0, 0);
      }
      acc[dt] = a;
    }
#endif
  }

  // --- epilogue: per-wave LDS transpose (no barrier needed), coalesced store
  float rl = 1.0f / lrow;
#pragma unroll
  for (int dt = 0; dt < 4; ++dt) {
    f32x4 v = acc[dt];
#pragma unroll
    for (int r = 0; r < 4; ++r) v[r] *= rl;
    *reinterpret_cast<f32x4*>(&Ol[wid][l15 * 68 + dt * 16 + lq * 4]) = v;
  }
  __builtin_amdgcn_s_waitcnt(0);  // lgkm drain (same-wave LDS RAW; conservative)
#pragma unroll
  for (int rep = 0; rep < 4; ++rep) {
    int q = rep * 4 + lq;
    f32x4 v = *reinterpret_cast<const f32x4*>(&Ol[wid][q * 68 + l15 * 4]);
    int t = q0 + q;
    if (t < SEQ)
      *reinterpret_cast<f32x4*>(&out[((size_t)b * SEQ + t) * DM + h * DH + l15 * 4]) = v;
  }
}

extern "C" void kernel_launch(void* const* d_in, const int* in_sizes, int n_in,
                              void* d_out, int out_size, void* d_ws, size_t ws_size,
                              hipStream_t stream) {
  (void)in_sizes; (void)n_in; (void)out_size; (void)ws_size;
  const float* X  = (const float*)d_in[0];
  const float* Wq = (const float*)d_in[1];
  const float* bq = (const float*)d_in[2];
  const float* Wk = (const float*)d_in[3];
  const float* bk = (const float*)d_in[4];
  const float* Wv = (const float*)d_in[5];
  const float* bv = (const float*)d_in[6];
  float* out = (float*)d_out;

  char* ws = (char*)d_ws;
  u16* Xb = (u16*)ws;
  u16* Wt = (u16*)(ws + 28366848);
  u16* Qw = (u16*)(ws + 28366848 + 3538944);
  u16* Kw = Qw + (size_t)NB * NH * SP * DH;
  u16* Vw = Kw + (size_t)NB * NH * SP * DH;

  cvt_x_kernel<<<dim3(13848), 256, 0, stream>>>(X, Xb, 3545088);
  cvt_w_kernel<<<dim3(2304, 3), 256, 0, stream>>>(Wq, Wk, Wv, Wt);
  qkv_gemm_kernel<<<dim3(160, 6, 3), 256, 0, stream>>>(Xb, Wt, bq, bk, bv, Qw, Kw, Vw);
  attn_kernel<<<dim3(10, NB * NH), 256, 0, stream>>>(Qw, Kw, Vw, out);
}

// Round 3
// 375.813 us; speedup vs baseline: 1.8168x; 1.8168x over previous
//
#include <hip/hip_runtime.h>

// B=32, S=577, D=768, H=12, Dh=64. fp32 in/out, bf16 MFMA compute.
#define NB 32
#define SEQ 577
#define SP 640      // padded seq (5*128, 10*64)
#define DM 768
#define NH 12
#define DH 64
#define NC 10       // key chunks of 64

typedef __attribute__((ext_vector_type(8))) short bf16x8;   // K=32 MFMA A/B frag
typedef __attribute__((ext_vector_type(4))) short bf16x4;   // K=16 MFMA A/B frag
typedef __attribute__((ext_vector_type(4))) float f32x4;
typedef __attribute__((ext_vector_type(2))) unsigned int u32x2;
typedef __attribute__((ext_vector_type(4))) unsigned int u32x4;
typedef unsigned short u16;

__device__ __forceinline__ u16 f2bf(float f) {  // RNE float->bf16
  unsigned int u = __builtin_bit_cast(unsigned int, f);
  u += 0x7fffu + ((u >> 16) & 1u);
  return (u16)(u >> 16);
}

// pack two fp32 -> bf16 pair (round-half-up) in one v_perm
__device__ __forceinline__ unsigned int pack_bf2(float a, float b) {
  unsigned int ua = __builtin_bit_cast(unsigned int, a) + 0x8000u;
  unsigned int ub = __builtin_bit_cast(unsigned int, b) + 0x8000u;
  return __builtin_amdgcn_perm(ub, ua, 0x07060302u);  // lo16=bf(a), hi16=bf(b)
}

__device__ __forceinline__ void g2l16(const void* g, void* lds) {
  __builtin_amdgcn_global_load_lds(
      (const __attribute__((address_space(1))) void*)g,
      (__attribute__((address_space(3))) void*)lds, 16, 0, 0);
}

// ---- kernel 1: fp32 -> bf16 cast of hidden_states -------------------------
__global__ void cvt_x_kernel(const float* __restrict__ X, u16* __restrict__ Xb, int n4) {
  int i = blockIdx.x * 256 + threadIdx.x;
  if (i >= n4) return;
  f32x4 v = *reinterpret_cast<const f32x4*>(X + (size_t)i * 4);
  u32x2 p;
  p[0] = (unsigned)f2bf(v[0]) | ((unsigned)f2bf(v[1]) << 16);
  p[1] = (unsigned)f2bf(v[2]) | ((unsigned)f2bf(v[3]) << 16);
  *reinterpret_cast<u32x2*>(Xb + (size_t)i * 4) = p;
}

// ---- kernel 2: cast + transpose weights: Wt[qkv][n][k] --------------------
__global__ void cvt_w_kernel(const float* __restrict__ Wq, const float* __restrict__ Wk,
                             const float* __restrict__ Wv, u16* __restrict__ Wt) {
  int idx = blockIdx.x * 256 + threadIdx.x;
  int m = blockIdx.y;
  const float* W = (m == 0) ? Wq : (m == 1) ? Wk : Wv;
  int k = idx / DM, n = idx - k * DM;
  Wt[(size_t)m * DM * DM + (size_t)n * DM + k] = f2bf(W[idx]);
}

// ---- kernel 3: fused QKV GEMM (bf16 MFMA, 128x128 tile, BK=32) ------------
__global__ __launch_bounds__(256)
void qkv_gemm_kernel(const u16* __restrict__ Xb, const u16* __restrict__ Wt,
                     const float* __restrict__ bq, const float* __restrict__ bk,
                     const float* __restrict__ bv,
                     u16* __restrict__ Qw, u16* __restrict__ Kw, u16* __restrict__ Vw) {
  __shared__ alignas(16) u16 As[128 * 32];
  __shared__ alignas(16) u16 Bs[128 * 32];

  const int tid = threadIdx.x;
  const int lane = tid & 63;
  const int wid = tid >> 6;
  const int wr = wid >> 1, wc = wid & 1;
  const int l15 = lane & 15, lq = lane >> 4;

  const int mt = blockIdx.x;
  const int nt = blockIdx.y;
  const int qkv = blockIdx.z;

  const int b = mt / 5;
  const int t0 = (mt - b * 5) * 128;
  const int n0 = nt * 128;

  const u16* Wm = Wt + (size_t)qkv * DM * DM;
  const float* bias = (qkv == 0) ? bq : (qkv == 1) ? bk : bv;

  int tA0 = t0 + wid * 16 + l15;
  int tA1 = t0 + (wid + 4) * 16 + l15;
  int xr0 = b * SEQ + (tA0 < SEQ ? tA0 : SEQ - 1);
  int xr1 = b * SEQ + (tA1 < SEQ ? tA1 : SEQ - 1);
  const u16* gA0 = Xb + (size_t)xr0 * DM + lq * 8;
  const u16* gA1 = Xb + (size_t)xr1 * DM + lq * 8;
  const u16* gB0 = Wm + (size_t)(n0 + wid * 16 + l15) * DM + lq * 8;
  const u16* gB1 = Wm + (size_t)(n0 + (wid + 4) * 16 + l15) * DM + lq * 8;
  u16* lA0 = &As[wid * 512];
  u16* lA1 = &As[(wid + 4) * 512];
  u16* lB0 = &Bs[wid * 512];
  u16* lB1 = &Bs[(wid + 4) * 512];

  f32x4 acc[4][4];
#pragma unroll
  for (int i = 0; i < 4; ++i)
#pragma unroll
    for (int j = 0; j < 4; ++j)
#pragma unroll
      for (int r = 0; r < 4; ++r) acc[i][j][r] = 0.0f;

  for (int k0 = 0; k0 < DM; k0 += 32) {
    g2l16(gA0 + k0, lA0);
    g2l16(gA1 + k0, lA1);
    g2l16(gB0 + k0, lB0);
    g2l16(gB1 + k0, lB1);
    __syncthreads();
    bf16x8 af[4], bfq[4];
#pragma unroll
    for (int i = 0; i < 4; ++i)
      af[i] = *reinterpret_cast<const bf16x8*>(&As[((wr * 4 + i) * 64 + lane) * 8]);
#pragma unroll
    for (int j = 0; j < 4; ++j)
      bfq[j] = *reinterpret_cast<const bf16x8*>(&Bs[((wc * 4 + j) * 64 + lane) * 8]);
#pragma unroll
    for (int i = 0; i < 4; ++i)
#pragma unroll
      for (int j = 0; j < 4; ++j)
        acc[i][j] = __builtin_amdgcn_mfma_f32_16x16x32_bf16(af[i], bfq[j], acc[i][j], 0, 0, 0);
    __syncthreads();
  }

  const float sfold = 0.18033688011112042f;  // (1/sqrt(64)) * log2(e)
#pragma unroll
  for (int j = 0; j < 4; ++j) {
    int col = n0 + wc * 64 + j * 16 + l15;
    int h = col >> 6;
    int d = col & 63;
    float bb = bias[col];
#pragma unroll
    for (int i = 0; i < 4; ++i) {
      int trow = t0 + wr * 64 + i * 16 + lq * 4;
      if (qkv == 2) {
        float v0 = acc[i][j][0] + bb, v1 = acc[i][j][1] + bb;
        float v2 = acc[i][j][2] + bb, v3 = acc[i][j][3] + bb;
        u32x2 p;
        p[0] = (unsigned)f2bf(v0) | ((unsigned)f2bf(v1) << 16);
        p[1] = (unsigned)f2bf(v2) | ((unsigned)f2bf(v3) << 16);
        size_t o = ((size_t)(b * NH + h) * DH + d) * SP + trow;
        *reinterpret_cast<u32x2*>(Vw + o) = p;
      } else {
        u16* dst = ((qkv == 0) ? Qw : Kw) + ((size_t)(b * NH + h) * SP + trow) * DH + d;
#pragma unroll
        for (int r = 0; r < 4; ++r) {
          float v = acc[i][j][r] + bb;
          if (qkv == 0) v *= sfold;
          dst[r * DH] = f2bf(v);
        }
      }
    }
  }
}

// ---- kernel 4: flash attention v3 -----------------------------------------
// Block = 4 waves = 128 queries (wave owns 32 = 2 q-tiles of 16).
// Per 64-key chunk: K staged via global_load_lds (fragment-ordered 16B/lane),
// V staged via VGPR->ds_write (fragment-ordered 8B/lane), double-buffered,
// one barrier per chunk (m97 structure). S^T = K·Q^T keeps softmax in-lane;
// P stays in-lane as the K=16 PV B-frag (O^T = Vt·P^T). Zero shuffles.
#if __has_builtin(__builtin_amdgcn_mfma_f32_16x16x16bf16_1k)
#define MFMA16(a, b, c) __builtin_amdgcn_mfma_f32_16x16x16bf16_1k(a, b, c, 0, 0, 0)
#define HAVE_MFMA16 1
#elif __has_builtin(__builtin_amdgcn_mfma_f32_16x16x16_bf16)
#define MFMA16(a, b, c) __builtin_amdgcn_mfma_f32_16x16x16_bf16(a, b, c, 0, 0, 0)
#define HAVE_MFMA16 1
#else
#define HAVE_MFMA16 0
#endif

__global__ __launch_bounds__(256)
void attn_kernel(const u16* __restrict__ Qw, const u16* __restrict__ Kw,
                 const u16* __restrict__ Vw, float* __restrict__ out) {
  // Kc: 8 entries (t,half) x 64 lanes x 16B = 8KB per buffer
  // Vc: 16 entries (dt,t)  x 64 lanes x  8B = 8KB per buffer
  __shared__ alignas(16) u16 Kc[2][8 * 64 * 8];
  __shared__ alignas(16) u16 Vc[2][16 * 64 * 4];

  const int tid = threadIdx.x;
  const int lane = tid & 63;
  const int wid = tid >> 6;
  const int l15 = lane & 15, lq = lane >> 4;
  const int bh = blockIdx.y;
  const int b = bh / NH;
  const int h = bh - b * NH;
  const int q0 = blockIdx.x * 128 + wid * 32;  // wave: queries q0..q0+31

  const u16* Qb = Qw + (size_t)bh * SP * DH;
  const u16* Kb = Kw + (size_t)bh * SP * DH;
  const u16* Vb = Vw + (size_t)bh * DH * SP;

  // Q B-frags: [qt][half], B[n=q=l15][k=half*32+lq*8+j]
  bf16x8 qf[2][2];
#pragma unroll
  for (int qt = 0; qt < 2; ++qt)
#pragma unroll
    for (int hf = 0; hf < 2; ++hf)
      qf[qt][hf] = *reinterpret_cast<const bf16x8*>(
          &Qb[(q0 + qt * 16 + l15) * DH + hf * 32 + lq * 8]);

  // staging source addresses (chunk-invariant parts)
  // K: wave stages entries e=2*wid+half: K[c0+wid*16+l15][half*32+lq*8..+8]
  const u16* gK = Kb + (size_t)(wid * 16 + l15) * DH + lq * 8;
  // V: wave stages entries e=4*wid+t: Vt[wid*16+l15][c0+t*16+lq*4..+4]
  const u16* gV = Vb + (size_t)(wid * 16 + l15) * SP + lq * 4;

  float mrow[2] = {-__builtin_inff(), -__builtin_inff()};
  float lrow[2] = {0.0f, 0.0f};
  f32x4 acc[2][4];  // [qt][dt]; d = dt*16+lq*4+r, q = q0+qt*16+l15
#pragma unroll
  for (int qt = 0; qt < 2; ++qt)
#pragma unroll
    for (int dt = 0; dt < 4; ++dt)
#pragma unroll
      for (int r = 0; r < 4; ++r) acc[qt][dt][r] = 0.0f;

  // ---- prologue: stage chunk 0 into buffer 0 ----
  g2l16(gK, &Kc[0][(wid * 2 + 0) * 512]);
  g2l16(gK + 32, &Kc[0][(wid * 2 + 1) * 512]);
  {
    u32x2 v[4];
#pragma unroll
    for (int t = 0; t < 4; ++t)
      v[t] = *reinterpret_cast<const u32x2*>(gV + t * 16);
#pragma unroll
    for (int t = 0; t < 4; ++t)
      *reinterpret_cast<u32x2*>(&Vc[0][((wid * 4 + t) * 64 + lane) * 4]) = v[t];
  }
  __syncthreads();

  for (int c = 0; c < NC; ++c) {
    const int cur = c & 1;
    const int c0 = c * 64;
    // ---- prefetch chunk c+1 (async; drained by end-of-loop barrier) ----
    u32x2 vn[4];
    if (c + 1 < NC) {
      const u16* gKn = gK + (size_t)(c0 + 64) * DH;
      g2l16(gKn, &Kc[cur ^ 1][(wid * 2 + 0) * 512]);
      g2l16(gKn + 32, &Kc[cur ^ 1][(wid * 2 + 1) * 512]);
#pragma unroll
      for (int t = 0; t < 4; ++t)
        vn[t] = *reinterpret_cast<const u32x2*>(gV + (c0 + 64) + t * 16);
    }

    // ---- S^T = K·Q^T from LDS K ----
    f32x4 s[2][4];
#pragma unroll
    for (int t = 0; t < 4; ++t) {
      bf16x8 kf0 = *reinterpret_cast<const bf16x8*>(&Kc[cur][((t * 2 + 0) * 64 + lane) * 8]);
      bf16x8 kf1 = *reinterpret_cast<const bf16x8*>(&Kc[cur][((t * 2 + 1) * 64 + lane) * 8]);
#pragma unroll
      for (int qt = 0; qt < 2; ++qt) {
        f32x4 z;
#pragma unroll
        for (int r = 0; r < 4; ++r) z[r] = 0.0f;
        z = __builtin_amdgcn_mfma_f32_16x16x32_bf16(kf0, qf[qt][0], z, 0, 0, 0);
        z = __builtin_amdgcn_mfma_f32_16x16x32_bf16(kf1, qf[qt][1], z, 0, 0, 0);
        s[qt][t] = z;
      }
    }
    // ---- mask padded keys (uniform branch, last chunk only) ----
    if (c0 + 64 > SEQ) {
#pragma unroll
      for (int qt = 0; qt < 2; ++qt)
#pragma unroll
        for (int t = 0; t < 4; ++t)
#pragma unroll
          for (int r = 0; r < 4; ++r) {
            int key = c0 + t * 16 + lq * 4 + r;
            s[qt][t][r] = (key < SEQ) ? s[qt][t][r] : -__builtin_inff();
          }
    }
    // ---- online softmax (in-lane over 16 + shfl 16,32) ----
    float alpha[2];
    unsigned int pku[2][4][2];
#pragma unroll
    for (int qt = 0; qt < 2; ++qt) {
      float mx = s[qt][0][0];
#pragma unroll
      for (int t = 0; t < 4; ++t)
#pragma unroll
        for (int r = 0; r < 4; ++r) mx = fmaxf(mx, s[qt][t][r]);
      mx = fmaxf(mx, __shfl_xor(mx, 16));
      mx = fmaxf(mx, __shfl_xor(mx, 32));
      float mn = fmaxf(mrow[qt], mx);
      alpha[qt] = __builtin_amdgcn_exp2f(mrow[qt] - mn);
      mrow[qt] = mn;
      float sm = 0.0f;
#pragma unroll
      for (int t = 0; t < 4; ++t) {
        float p0 = __builtin_amdgcn_exp2f(s[qt][t][0] - mn);
        float p1 = __builtin_amdgcn_exp2f(s[qt][t][1] - mn);
        float p2 = __builtin_amdgcn_exp2f(s[qt][t][2] - mn);
        float p3 = __builtin_amdgcn_exp2f(s[qt][t][3] - mn);
        sm += (p0 + p1) + (p2 + p3);
        pku[qt][t][0] = pack_bf2(p0, p1);
        pku[qt][t][1] = pack_bf2(p2, p3);
      }
      sm += __shfl_xor(sm, 16);
      sm += __shfl_xor(sm, 32);
      lrow[qt] = lrow[qt] * alpha[qt] + sm;
    }

#if HAVE_MFMA16
    // ---- PV: O^T = Vt·P^T (K=16 MFMA; vf shared across q-tiles) ----
#pragma unroll
    for (int dt = 0; dt < 4; ++dt) {
      bf16x4 vf[4];
#pragma unroll
      for (int t = 0; t < 4; ++t)
        vf[t] = *reinterpret_cast<const bf16x4*>(&Vc[cur][((dt * 4 + t) * 64 + lane) * 4]);
#pragma unroll
      for (int qt = 0; qt < 2; ++qt) {
        f32x4 a = acc[qt][dt];
#pragma unroll
        for (int r = 0; r < 4; ++r) a[r] *= alpha[qt];
#pragma unroll
        for (int t = 0; t < 4; ++t) {
          bf16x4 pf = __builtin_bit_cast(bf16x4, u32x2{pku[qt][t][0], pku[qt][t][1]});
          a = MFMA16(vf[t], pf, a);
        }
        acc[qt][dt] = a;
      }
    }
#else
    // ---- fallback: K=32 MFMA, B-frag via bpermute (v2-verified pattern) ----
#pragma unroll
    for (int qt = 0; qt < 2; ++qt) {
      unsigned int bfrag[2][4];
#pragma unroll
      for (int hh = 0; hh < 2; ++hh)
#pragma unroll
        for (int w = 0; w < 4; ++w) {
          int srcl = l15 + 16 * (2 * (lq & 1) + (w >> 1));
          unsigned int lo = (unsigned int)__shfl((int)pku[qt][2 * hh][w & 1], srcl);
          unsigned int hi = (unsigned int)__shfl((int)pku[qt][2 * hh + 1][w & 1], srcl);
          bfrag[hh][w] = (lq < 2) ? lo : hi;
        }
#pragma unroll
      for (int dt = 0; dt < 4; ++dt) {
        f32x4 a = acc[qt][dt];
#pragma unroll
        for (int r = 0; r < 4; ++r) a[r] *= alpha[qt];
#pragma unroll
        for (int hh = 0; hh < 2; ++hh) {
          u32x2 w0 = *reinterpret_cast<const u32x2*>(&Vc[cur][((dt * 4 + 2 * hh) * 64 + lane) * 4]);
          u32x2 w1 = *reinterpret_cast<const u32x2*>(&Vc[cur][((dt * 4 + 2 * hh + 1) * 64 + lane) * 4]);
          u32x4 vw = {w0[0], w0[1], w1[0], w1[1]};
          u32x4 pw = {bfrag[hh][0], bfrag[hh][1], bfrag[hh][2], bfrag[hh][3]};
          a = __builtin_amdgcn_mfma_f32_16x16x32_bf16(
              __builtin_bit_cast(bf16x8, vw), __builtin_bit_cast(bf16x8, pw), a, 0, 0, 0);
        }
        acc[qt][dt] = a;
      }
    }
#endif

    // ---- write prefetched V into the other buffer, then barrier ----
    if (c + 1 < NC) {
#pragma unroll
      for (int t = 0; t < 4; ++t)
        *reinterpret_cast<u32x2*>(&Vc[cur ^ 1][((wid * 4 + t) * 64 + lane) * 4]) = vn[t];
    }
    __syncthreads();
  }

  // ---- epilogue: direct stores (lane holds 4 consecutive d -> 16B store) ----
#pragma unroll
  for (int qt = 0; qt < 2; ++qt) {
    int q = q0 + qt * 16 + l15;
    if (q < SEQ) {
      float rl = 1.0f / lrow[qt];
      float* orow = out + ((size_t)b * SEQ + q) * DM + h * DH;
#pragma unroll
      for (int dt = 0; dt < 4; ++dt) {
        f32x4 v = acc[qt][dt];
#pragma unroll
        for (int r = 0; r < 4; ++r) v[r] *= rl;
        *reinterpret_cast<f32x4*>(&orow[dt * 16 + lq * 4]) = v;
      }
    }
  }
}

extern "C" void kernel_launch(void* const* d_in, const int* in_sizes, int n_in,
                              void* d_out, int out_size, void* d_ws, size_t ws_size,
                              hipStream_t stream) {
  (void)in_sizes; (void)n_in; (void)out_size; (void)ws_size;
  const float* X  = (const float*)d_in[0];
  const float* Wq = (const float*)d_in[1];
  const float* bq = (const float*)d_in[2];
  const float* Wk = (const float*)d_in[3];
  const float* bk = (const float*)d_in[4];
  const float* Wv = (const float*)d_in[5];
  const float* bv = (const float*)d_in[6];
  float* out = (float*)d_out;

  char* ws = (char*)d_ws;
  u16* Xb = (u16*)ws;
  u16* Wt = (u16*)(ws + 28366848);
  u16* Qw = (u16*)(ws + 28366848 + 3538944);
  u16* Kw = Qw + (size_t)NB * NH * SP * DH;
  u16* Vw = Kw + (size_t)NB * NH * SP * DH;

  cvt_x_kernel<<<dim3(13848), 256, 0, stream>>>(X, Xb, 3545088);
  cvt_w_kernel<<<dim3(2304, 3), 256, 0, stream>>>(Wq, Wk, Wv, Wt);
  qkv_gemm_kernel<<<dim3(160, 6, 3), 256, 0, stream>>>(Xb, Wt, bq, bk, bv, Qw, Kw, Vw);
  attn_kernel<<<dim3(5, NB * NH), 256, 0, stream>>>(Qw, Kw, Vw, out);
}